// Round 1
// baseline (1190.604 us; speedup 1.0000x reference)
//
#include <hip/hip_runtime.h>
#include <math.h>

// Problem constants
#define BB   2
#define SS   2048
#define DD   1024
#define NHH  4
#define DHH  256
#define BHH  (BB*NHH)

// Workspace layout (float offsets). Total = 3*4194304 + 5*16384 floats = 50,659,328 bytes (~48.4 MB)
#define Q_OFF   0
#define K_OFF   (BB*NHH*SS*DHH)
#define V_OFF   (2*BB*NHH*SS*DHH)
#define IG_OFF  (3*BB*NHH*SS*DHH)
#define LSF_OFF (IG_OFF + BHH*SS)
#define A_OFF   (LSF_OFF + BHH*SS)
#define M_OFF   (A_OFF + BHH*SS)
#define FLR_OFF (M_OFF + BHH*SS)

// ---------------------------------------------------------------------------
// Kernel 1: headwise QKV projection (per-4-channel 4x4 matmuls) + gate GEMVs.
// One block per (b,s) row; thread t == qkv-head t (256 heads of width 4).
// k is pre-scaled by 1/sqrt(DH) = 1/16. Gates reduced across block.
// ---------------------------------------------------------------------------
__global__ __launch_bounds__(256) void k_proj(
    const float* __restrict__ x,
    const float* __restrict__ wq, const float* __restrict__ wk, const float* __restrict__ wv,
    const float* __restrict__ wi, const float* __restrict__ bi,
    const float* __restrict__ wf, const float* __restrict__ bf,
    float* __restrict__ ws)
{
  const int row = blockIdx.x;          // b*SS + s
  const int b   = row >> 11;
  const int s   = row & (SS-1);
  const int g   = threadIdx.x;         // qkv head 0..255

  const float4 xv = *(const float4*)(x + (size_t)row*DD + (g<<2));

  const int h   = g >> 6;              // master head
  const int dh0 = (g & 63) << 2;       // channel within head
  const size_t qi = ((size_t)(b*NHH + h)*SS + s)*DHH + dh0;

  // q
  {
    const float4 w0 = *(const float4*)(wq + g*16 + 0);
    const float4 w1 = *(const float4*)(wq + g*16 + 4);
    const float4 w2 = *(const float4*)(wq + g*16 + 8);
    const float4 w3 = *(const float4*)(wq + g*16 + 12);
    float4 r;
    r.x = w0.x*xv.x + w0.y*xv.y + w0.z*xv.z + w0.w*xv.w;
    r.y = w1.x*xv.x + w1.y*xv.y + w1.z*xv.z + w1.w*xv.w;
    r.z = w2.x*xv.x + w2.y*xv.y + w2.z*xv.z + w2.w*xv.w;
    r.w = w3.x*xv.x + w3.y*xv.y + w3.z*xv.z + w3.w*xv.w;
    *(float4*)(ws + Q_OFF + qi) = r;
  }
  // k (scaled by 1/16)
  {
    const float4 w0 = *(const float4*)(wk + g*16 + 0);
    const float4 w1 = *(const float4*)(wk + g*16 + 4);
    const float4 w2 = *(const float4*)(wk + g*16 + 8);
    const float4 w3 = *(const float4*)(wk + g*16 + 12);
    float4 r;
    r.x = 0.0625f*(w0.x*xv.x + w0.y*xv.y + w0.z*xv.z + w0.w*xv.w);
    r.y = 0.0625f*(w1.x*xv.x + w1.y*xv.y + w1.z*xv.z + w1.w*xv.w);
    r.z = 0.0625f*(w2.x*xv.x + w2.y*xv.y + w2.z*xv.z + w2.w*xv.w);
    r.w = 0.0625f*(w3.x*xv.x + w3.y*xv.y + w3.z*xv.z + w3.w*xv.w);
    *(float4*)(ws + K_OFF + qi) = r;
  }
  // v
  {
    const float4 w0 = *(const float4*)(wv + g*16 + 0);
    const float4 w1 = *(const float4*)(wv + g*16 + 4);
    const float4 w2 = *(const float4*)(wv + g*16 + 8);
    const float4 w3 = *(const float4*)(wv + g*16 + 12);
    float4 r;
    r.x = w0.x*xv.x + w0.y*xv.y + w0.z*xv.z + w0.w*xv.w;
    r.y = w1.x*xv.x + w1.y*xv.y + w1.z*xv.z + w1.w*xv.w;
    r.z = w2.x*xv.x + w2.y*xv.y + w2.z*xv.z + w2.w*xv.w;
    r.w = w3.x*xv.x + w3.y*xv.y + w3.z*xv.z + w3.w*xv.w;
    *(float4*)(ws + V_OFF + qi) = r;
  }

  // gates: ig/fg[n] = x . (wi[n,0:D]+wi[n,D:2D]+wi[n,2D:3D]) + bias
  float pi[4], pf[4];
  const int c = g << 2;
  #pragma unroll
  for (int n=0;n<4;n++) {
    const float* wip = wi + n*3*DD + c;
    const float* wfp = wf + n*3*DD + c;
    const float4 a0 = *(const float4*)(wip);
    const float4 a1 = *(const float4*)(wip + DD);
    const float4 a2 = *(const float4*)(wip + 2*DD);
    pi[n] = (a0.x+a1.x+a2.x)*xv.x + (a0.y+a1.y+a2.y)*xv.y
          + (a0.z+a1.z+a2.z)*xv.z + (a0.w+a1.w+a2.w)*xv.w;
    const float4 b0 = *(const float4*)(wfp);
    const float4 b1 = *(const float4*)(wfp + DD);
    const float4 b2 = *(const float4*)(wfp + 2*DD);
    pf[n] = (b0.x+b1.x+b2.x)*xv.x + (b0.y+b1.y+b2.y)*xv.y
          + (b0.z+b1.z+b2.z)*xv.z + (b0.w+b1.w+b2.w)*xv.w;
  }
  #pragma unroll
  for (int off=32; off>0; off>>=1) {
    #pragma unroll
    for (int n=0;n<4;n++) {
      pi[n] += __shfl_down(pi[n], off);
      pf[n] += __shfl_down(pf[n], off);
    }
  }
  __shared__ float red[4][8];
  const int lane = g & 63, wid = g >> 6;
  if (lane == 0) {
    #pragma unroll
    for (int n=0;n<4;n++) { red[wid][n] = pi[n]; red[wid][4+n] = pf[n]; }
  }
  __syncthreads();
  if (g < 4) {
    const int n = g;
    float ti = red[0][n]+red[1][n]+red[2][n]+red[3][n] + bi[n];
    float tf = red[0][4+n]+red[1][4+n]+red[2][4+n]+red[3][4+n] + bf[n];
    ws[IG_OFF + (size_t)(b*NHH+n)*SS + s] = ti;
    // log_sigmoid, stable
    float ls = (tf >= 0.f) ? -log1pf(expf(-tf)) : (tf - log1pf(expf(tf)));
    ws[LSF_OFF + (size_t)(b*NHH+n)*SS + s] = ls;
  }
}

// ---------------------------------------------------------------------------
// Kernel 2: per-(b,head) scan. cs = inclusive cumsum(log_sigmoid(fg));
// a[t] = ig[t]-cs[t]; m[s] = prefix-max(a); floor[s] = exp(-(cs[s]+m[s])).
// ---------------------------------------------------------------------------
__global__ __launch_bounds__(256) void k_scan(float* __restrict__ ws)
{
  const int bh = blockIdx.x;
  const int tid = threadIdx.x;
  const float* igp = ws + IG_OFF + (size_t)bh*SS;
  const float* lsp = ws + LSF_OFF + (size_t)bh*SS;
  float* ap = ws + A_OFF  + (size_t)bh*SS;
  float* mp = ws + M_OFF  + (size_t)bh*SS;
  float* fp = ws + FLR_OFF+ (size_t)bh*SS;

  __shared__ float sb[256];
  const int base = tid*8;
  float l[8], c[8];
  #pragma unroll
  for (int j=0;j<8;j++) l[j] = lsp[base+j];
  c[0] = l[0];
  #pragma unroll
  for (int j=1;j<8;j++) c[j] = c[j-1] + l[j];

  sb[tid] = c[7];
  __syncthreads();
  for (int off=1; off<256; off<<=1) {
    float v = sb[tid];
    float u = (tid>=off) ? sb[tid-off] : 0.f;
    __syncthreads();
    sb[tid] = v + u;
    __syncthreads();
  }
  const float exs = (tid==0) ? 0.f : sb[tid-1];

  float cs[8], aa[8], mx[8];
  #pragma unroll
  for (int j=0;j<8;j++) { cs[j] = exs + c[j]; aa[j] = igp[base+j] - cs[j]; }
  mx[0] = aa[0];
  #pragma unroll
  for (int j=1;j<8;j++) mx[j] = fmaxf(mx[j-1], aa[j]);

  __syncthreads();
  sb[tid] = mx[7];
  __syncthreads();
  for (int off=1; off<256; off<<=1) {
    float v = sb[tid];
    float u = (tid>=off) ? sb[tid-off] : -INFINITY;
    __syncthreads();
    sb[tid] = fmaxf(v, u);
    __syncthreads();
  }
  const float exm = (tid==0) ? -INFINITY : sb[tid-1];

  #pragma unroll
  for (int j=0;j<8;j++) {
    float mm = fmaxf(exm, mx[j]);
    ap[base+j] = aa[j];
    mp[base+j] = mm;
    fp[base+j] = expf(-(cs[j] + mm));
  }
}

// ---------------------------------------------------------------------------
// Kernel 3: causal weighted contraction + normalizer + fused per-head LN.
// 32x32 tiles; Q,K staged in LDS (pad +4 floats keeps float4 alignment and
// 2-way-max bank aliasing, which is free); V streamed from L2 (2MB/head,
// head pinned to one XCD via blockIdx.x=head); W tile in LDS; tiles
// processed largest-first for load balance.
// ---------------------------------------------------------------------------
#define BM 32
#define BN 32
#define KPAD 260
#define WPAD 33
#define SMEM_FLOATS (2*BM*KPAD + BM*WPAD + BM + BM + 256 + 256)

__global__ __launch_bounds__(256) void k_attn(
    const float* __restrict__ ws, const float* __restrict__ ln_w,
    float* __restrict__ out)
{
  extern __shared__ float sm[];
  float* Qt  = sm;                 // BM*KPAD
  float* Kt  = Qt + BM*KPAD;       // BM*KPAD
  float* Wt  = Kt + BM*KPAD;       // BM*WPAD
  float* aL  = Wt + BM*WPAD;       // BM
  float* mL  = aL + BM;            // BM
  float* red1= mL + BM;            // 256
  float* red2= red1 + 256;         // 256
  float* stg = Qt;                 // reused for output staging

  const int bh   = blockIdx.x;         // 0..7 : b*NH+h (one head per XCD)
  const int b    = bh >> 2;
  const int h    = bh & 3;
  const int tile = (int)(gridDim.y - 1 - blockIdx.y);  // largest tiles first
  const int s0   = tile * BM;
  const int tid  = threadIdx.x;

  const float* qb = ws + Q_OFF + (size_t)bh*SS*DHH;
  const float* kb = ws + K_OFF + (size_t)bh*SS*DHH;
  const float* vb = ws + V_OFF + (size_t)bh*SS*DHH;
  const float* ab = ws + A_OFF + (size_t)bh*SS;
  const float* mb = ws + M_OFF + (size_t)bh*SS;
  const float* fb = ws + FLR_OFF + (size_t)bh*SS;

  // stage Q tile
  #pragma unroll
  for (int j=0;j<8;j++) {
    int f = tid + j*256;
    int r = f >> 6, c4 = (f & 63) << 2;
    *(float4*)(Qt + r*KPAD + c4) = *(const float4*)(qb + (size_t)(s0+r)*DHH + c4);
  }
  if (tid < BM) mL[tid] = mb[s0 + tid];

  const int ty = tid >> 4, tx = tid & 15;          // phase A: 2x2 reg tiles
  const int rB = tid & 31, chunk = tid >> 5;       // phase B: row x 32-ch slice
  const int ch0 = chunk << 5;

  float acc[32];
  #pragma unroll
  for (int i=0;i<32;i++) acc[i] = 0.f;
  float den = 0.f;

  for (int t0 = 0; t0 <= s0; t0 += BN) {
    __syncthreads();   // protect Kt/aL/Wt overwrite vs previous iteration
    #pragma unroll
    for (int j=0;j<8;j++) {
      int f = tid + j*256;
      int r = f >> 6, c4 = (f & 63) << 2;
      *(float4*)(Kt + r*KPAD + c4) = *(const float4*)(kb + (size_t)(t0+r)*DHH + c4);
    }
    if (tid < BN) aL[tid] = ab[t0 + tid];
    __syncthreads();

    // phase A: S-tile = Q . K^T (k pre-scaled), then weights w = qk*exp(a-m)
    float s00=0.f, s01=0.f, s10=0.f, s11=0.f;
    #pragma unroll 8
    for (int d=0; d<DHH; d+=4) {
      float4 qa = *(const float4*)(Qt + ty*KPAD + d);
      float4 qc = *(const float4*)(Qt + (ty+16)*KPAD + d);
      float4 ka = *(const float4*)(Kt + tx*KPAD + d);
      float4 kc = *(const float4*)(Kt + (tx+16)*KPAD + d);
      s00 += qa.x*ka.x + qa.y*ka.y + qa.z*ka.z + qa.w*ka.w;
      s01 += qa.x*kc.x + qa.y*kc.y + qa.z*kc.z + qa.w*kc.w;
      s10 += qc.x*ka.x + qc.y*ka.y + qc.z*ka.z + qc.w*ka.w;
      s11 += qc.x*kc.x + qc.y*kc.y + qc.z*kc.z + qc.w*kc.w;
    }
    {
      const int sr0 = s0+ty, sr1 = s0+ty+16, tc0 = t0+tx, tc1 = t0+tx+16;
      const float m0 = mL[ty], m1 = mL[ty+16];
      const float a0 = aL[tx], a1 = aL[tx+16];
      Wt[ty*WPAD + tx]         = (tc0<=sr0) ? s00*expf(a0-m0) : 0.f;
      Wt[ty*WPAD + tx+16]      = (tc1<=sr0) ? s01*expf(a1-m0) : 0.f;
      Wt[(ty+16)*WPAD + tx]    = (tc0<=sr1) ? s10*expf(a0-m1) : 0.f;
      Wt[(ty+16)*WPAD + tx+16] = (tc1<=sr1) ? s11*expf(a1-m1) : 0.f;
    }
    __syncthreads();

    // phase B: acc += W . V ; den += row-sum(W). V streamed from L2.
    const float* vt = vb + (size_t)t0*DHH + ch0;
    for (int t=0;t<BN;t++) {
      float wv = Wt[rB*WPAD + t];
      den += wv;
      const float4* vp = (const float4*)(vt + (size_t)t*DHH);
      #pragma unroll
      for (int c4=0;c4<8;c4++) {
        float4 vv = vp[c4];
        acc[c4*4+0] += wv*vv.x;
        acc[c4*4+1] += wv*vv.y;
        acc[c4*4+2] += wv*vv.z;
        acc[c4*4+3] += wv*vv.w;
      }
    }
  }

  // epilogue: normalizer + per-head layernorm + transposed coalesced write
  const float flr = fb[s0 + rB];
  const float inv = 1.f / (fmaxf(fabsf(den), flr) + 1e-8f);
  float val[32], s1 = 0.f, s2 = 0.f;
  #pragma unroll
  for (int i=0;i<32;i++) { val[i] = acc[i]*inv; s1 += val[i]; s2 += val[i]*val[i]; }
  __syncthreads();
  red1[rB*8 + chunk] = s1;
  red2[rB*8 + chunk] = s2;
  __syncthreads();
  float ms = 0.f, sq = 0.f;
  #pragma unroll
  for (int j=0;j<8;j++) { ms += red1[rB*8+j]; sq += red2[rB*8+j]; }
  const float mean = ms * (1.f/DHH);
  const float var  = sq * (1.f/DHH) - mean*mean;
  const float rstd = rsqrtf(var + 1e-5f);
  #pragma unroll
  for (int i=0;i<32;i++) {
    float gmm = 1.f + ln_w[h*DHH + ch0 + i];
    stg[rB*KPAD + ch0 + i] = (val[i]-mean)*rstd*gmm;
  }
  __syncthreads();
  for (int r2=0;r2<BM;r2++) {
    out[((size_t)(b*SS + s0 + r2))*DD + h*DHH + tid] = stg[r2*KPAD + tid];
  }
}

// ---------------------------------------------------------------------------
extern "C" void kernel_launch(void* const* d_in, const int* in_sizes, int n_in,
                              void* d_out, int out_size, void* d_ws, size_t ws_size,
                              hipStream_t stream) {
  (void)in_sizes; (void)n_in; (void)out_size; (void)ws_size;
  const float* x    = (const float*)d_in[0];
  const float* wq   = (const float*)d_in[1];
  const float* wk   = (const float*)d_in[2];
  const float* wv   = (const float*)d_in[3];
  const float* wi   = (const float*)d_in[4];
  const float* bi   = (const float*)d_in[5];
  const float* wf   = (const float*)d_in[6];
  const float* bf   = (const float*)d_in[7];
  const float* ln_w = (const float*)d_in[8];
  float* out = (float*)d_out;
  float* ws  = (float*)d_ws;   // needs ~48.4 MB

  k_proj<<<BB*SS, 256, 0, stream>>>(x, wq, wk, wv, wi, bi, wf, bf, ws);
  k_scan<<<BHH, 256, 0, stream>>>(ws);
  dim3 g3(BHH, SS/BM);
  k_attn<<<g3, 256, SMEM_FLOATS*sizeof(float), stream>>>(ws, ln_w, out);
}

// Round 2
// 163.372 us; speedup vs baseline: 7.2877x; 7.2877x over previous
//
#include <hip/hip_runtime.h>
#include <math.h>

// ---------------------------------------------------------------------------
// mLSTM cell, MFMA bf16 version.
// Pipeline: k_proj (fp32->bf16 QKV + gate GEMVs) -> k_scan (cumsum/prefix-max)
//           -> k_vt (V transpose) -> memset(acc) -> k_attn (MFMA, split-K,
//           atomic fp32 accumulate) -> k_fin (normalizer + headwise LN).
// Key identities: log_D[s,t] = cs[s] + a[t], a[t]=ig[t]-cs[t], m[s]=prefmax a,
//   D = exp(a[t]-m[s]) (<=1), floor[s] = exp(-(cs[s]+m[s])). All additive in t
//   -> split-K with atomicAdd is exact (modulo fp ordering).
// ---------------------------------------------------------------------------

#define BB   2
#define SS   2048
#define DD   1024
#define NHH  4
#define DHH  256
#define BHH  (BB*NHH)

// Workspace byte offsets (total 42,336,256 B; round-1 used 50.6 MB OK)
#define QB_OFF   ((size_t)0)
#define KB_OFF   ((size_t)8  << 20)
#define VT_OFF   ((size_t)16 << 20)
#define VB_OFF   ((size_t)24 << 20)   // dies after k_vt; overlaid by ACC
#define ACC_OFF  ((size_t)24 << 20)   // 16 MB fp32, zeroed after k_vt
#define DEN_OFF  ((size_t)40 << 20)   // 64 KB fp32
#define IG_OFF   (DEN_OFF + ((size_t)64<<10))
#define LSF_OFF  (IG_OFF  + ((size_t)64<<10))
#define AA_OFF   (LSF_OFF + ((size_t)64<<10))
#define MM_OFF   (AA_OFF  + ((size_t)64<<10))
#define FLR_OFF  (MM_OFF  + ((size_t)64<<10))

typedef __attribute__((ext_vector_type(8))) short short8;   // 8 bf16 (4 VGPR)
typedef __attribute__((ext_vector_type(4))) float f32x4;

typedef const __attribute__((address_space(1))) unsigned int* gas1_u32;
typedef __attribute__((address_space(3))) unsigned int* las3_u32;

__device__ __forceinline__ unsigned short f2b(float f) {
  union { float f; unsigned int u; } v; v.f = f;
  unsigned int r = (v.u + 0x7FFFu + ((v.u >> 16) & 1u)) >> 16;
  return (unsigned short)r;
}

__device__ __forceinline__ void gload_lds16(void* lds, const void* g) {
  __builtin_amdgcn_global_load_lds((gas1_u32)g, (las3_u32)lds, 16, 0, 0);
}

// ---------------------------------------------------------------------------
// Kernel 1: headwise QKV projection (4x4 blocks) + gate GEMVs. bf16 outputs.
// ---------------------------------------------------------------------------
__global__ __launch_bounds__(256) void k_proj(
    const float* __restrict__ x,
    const float* __restrict__ wq, const float* __restrict__ wk, const float* __restrict__ wv,
    const float* __restrict__ wi, const float* __restrict__ bi,
    const float* __restrict__ wf, const float* __restrict__ bf,
    unsigned short* __restrict__ qb, unsigned short* __restrict__ kb,
    unsigned short* __restrict__ vb, float* __restrict__ ig, float* __restrict__ lsf)
{
  const int row = blockIdx.x;          // b*SS + s
  const int b   = row >> 11;
  const int s   = row & (SS-1);
  const int g   = threadIdx.x;         // qkv head 0..255

  const float4 xv = *(const float4*)(x + (size_t)row*DD + (g<<2));

  const int h   = g >> 6;
  const int dh0 = (g & 63) << 2;
  const size_t qi = ((size_t)(b*NHH + h)*SS + s)*DHH + dh0;

  {
    const float4 w0 = *(const float4*)(wq + g*16 + 0);
    const float4 w1 = *(const float4*)(wq + g*16 + 4);
    const float4 w2 = *(const float4*)(wq + g*16 + 8);
    const float4 w3 = *(const float4*)(wq + g*16 + 12);
    ushort4 r;
    r.x = f2b(w0.x*xv.x + w0.y*xv.y + w0.z*xv.z + w0.w*xv.w);
    r.y = f2b(w1.x*xv.x + w1.y*xv.y + w1.z*xv.z + w1.w*xv.w);
    r.z = f2b(w2.x*xv.x + w2.y*xv.y + w2.z*xv.z + w2.w*xv.w);
    r.w = f2b(w3.x*xv.x + w3.y*xv.y + w3.z*xv.z + w3.w*xv.w);
    *(ushort4*)(qb + qi) = r;
  }
  {
    const float4 w0 = *(const float4*)(wk + g*16 + 0);
    const float4 w1 = *(const float4*)(wk + g*16 + 4);
    const float4 w2 = *(const float4*)(wk + g*16 + 8);
    const float4 w3 = *(const float4*)(wk + g*16 + 12);
    ushort4 r;
    r.x = f2b(0.0625f*(w0.x*xv.x + w0.y*xv.y + w0.z*xv.z + w0.w*xv.w));
    r.y = f2b(0.0625f*(w1.x*xv.x + w1.y*xv.y + w1.z*xv.z + w1.w*xv.w));
    r.z = f2b(0.0625f*(w2.x*xv.x + w2.y*xv.y + w2.z*xv.z + w2.w*xv.w));
    r.w = f2b(0.0625f*(w3.x*xv.x + w3.y*xv.y + w3.z*xv.z + w3.w*xv.w));
    *(ushort4*)(kb + qi) = r;
  }
  {
    const float4 w0 = *(const float4*)(wv + g*16 + 0);
    const float4 w1 = *(const float4*)(wv + g*16 + 4);
    const float4 w2 = *(const float4*)(wv + g*16 + 8);
    const float4 w3 = *(const float4*)(wv + g*16 + 12);
    ushort4 r;
    r.x = f2b(w0.x*xv.x + w0.y*xv.y + w0.z*xv.z + w0.w*xv.w);
    r.y = f2b(w1.x*xv.x + w1.y*xv.y + w1.z*xv.z + w1.w*xv.w);
    r.z = f2b(w2.x*xv.x + w2.y*xv.y + w2.z*xv.z + w2.w*xv.w);
    r.w = f2b(w3.x*xv.x + w3.y*xv.y + w3.z*xv.z + w3.w*xv.w);
    *(ushort4*)(vb + qi) = r;
  }

  float pi[4], pf[4];
  const int c = g << 2;
  #pragma unroll
  for (int n=0;n<4;n++) {
    const float* wip = wi + n*3*DD + c;
    const float* wfp = wf + n*3*DD + c;
    const float4 a0 = *(const float4*)(wip);
    const float4 a1 = *(const float4*)(wip + DD);
    const float4 a2 = *(const float4*)(wip + 2*DD);
    pi[n] = (a0.x+a1.x+a2.x)*xv.x + (a0.y+a1.y+a2.y)*xv.y
          + (a0.z+a1.z+a2.z)*xv.z + (a0.w+a1.w+a2.w)*xv.w;
    const float4 b0 = *(const float4*)(wfp);
    const float4 b1 = *(const float4*)(wfp + DD);
    const float4 b2 = *(const float4*)(wfp + 2*DD);
    pf[n] = (b0.x+b1.x+b2.x)*xv.x + (b0.y+b1.y+b2.y)*xv.y
          + (b0.z+b1.z+b2.z)*xv.z + (b0.w+b1.w+b2.w)*xv.w;
  }
  #pragma unroll
  for (int off=32; off>0; off>>=1) {
    #pragma unroll
    for (int n=0;n<4;n++) {
      pi[n] += __shfl_down(pi[n], off);
      pf[n] += __shfl_down(pf[n], off);
    }
  }
  __shared__ float red[4][8];
  const int lane = g & 63, wid = g >> 6;
  if (lane == 0) {
    #pragma unroll
    for (int n=0;n<4;n++) { red[wid][n] = pi[n]; red[wid][4+n] = pf[n]; }
  }
  __syncthreads();
  if (g < 4) {
    const int n = g;
    float ti = red[0][n]+red[1][n]+red[2][n]+red[3][n] + bi[n];
    float tf = red[0][4+n]+red[1][4+n]+red[2][4+n]+red[3][4+n] + bf[n];
    ig[(size_t)(b*NHH+n)*SS + s] = ti;
    float ls = (tf >= 0.f) ? -log1pf(expf(-tf)) : (tf - log1pf(expf(tf)));
    lsf[(size_t)(b*NHH+n)*SS + s] = ls;
  }
}

// ---------------------------------------------------------------------------
// Kernel 2: per-(b,head) scan.
// ---------------------------------------------------------------------------
__global__ __launch_bounds__(256) void k_scan(
    const float* __restrict__ ig, const float* __restrict__ lsf,
    float* __restrict__ aa, float* __restrict__ mm, float* __restrict__ flr)
{
  const int bh = blockIdx.x;
  const int tid = threadIdx.x;
  const float* igp = ig + (size_t)bh*SS;
  const float* lsp = lsf + (size_t)bh*SS;
  float* ap = aa + (size_t)bh*SS;
  float* mp = mm + (size_t)bh*SS;
  float* fp = flr + (size_t)bh*SS;

  __shared__ float sb[256];
  const int base = tid*8;
  float l[8], c[8];
  #pragma unroll
  for (int j=0;j<8;j++) l[j] = lsp[base+j];
  c[0] = l[0];
  #pragma unroll
  for (int j=1;j<8;j++) c[j] = c[j-1] + l[j];

  sb[tid] = c[7];
  __syncthreads();
  for (int off=1; off<256; off<<=1) {
    float v = sb[tid];
    float u = (tid>=off) ? sb[tid-off] : 0.f;
    __syncthreads();
    sb[tid] = v + u;
    __syncthreads();
  }
  const float exs = (tid==0) ? 0.f : sb[tid-1];

  float cs[8], a8[8], mx[8];
  #pragma unroll
  for (int j=0;j<8;j++) { cs[j] = exs + c[j]; a8[j] = igp[base+j] - cs[j]; }
  mx[0] = a8[0];
  #pragma unroll
  for (int j=1;j<8;j++) mx[j] = fmaxf(mx[j-1], a8[j]);

  __syncthreads();
  sb[tid] = mx[7];
  __syncthreads();
  for (int off=1; off<256; off<<=1) {
    float v = sb[tid];
    float u = (tid>=off) ? sb[tid-off] : -INFINITY;
    __syncthreads();
    sb[tid] = fmaxf(v, u);
    __syncthreads();
  }
  const float exm = (tid==0) ? -INFINITY : sb[tid-1];

  #pragma unroll
  for (int j=0;j<8;j++) {
    float mmx = fmaxf(exm, mx[j]);
    ap[base+j] = a8[j];
    mp[base+j] = mmx;
    fp[base+j] = expf(-(cs[j] + mmx));
  }
}

// ---------------------------------------------------------------------------
// Kernel 3: transpose V bf16 [bh][s][d] -> Vt [bh][d][s].
// ---------------------------------------------------------------------------
__global__ __launch_bounds__(256) void k_vt(
    const unsigned short* __restrict__ vb, unsigned short* __restrict__ vt)
{
  __shared__ unsigned short tile[64][72];
  const int bh = blockIdx.x, st = blockIdx.y, dt = blockIdx.z;
  const int s0 = st*64, d0 = dt*64;
  const unsigned short* src = vb + ((size_t)bh*SS + s0)*DHH + d0;
  #pragma unroll
  for (int j=0;j<2;j++){
    int f = threadIdx.x + j*256;           // 0..511
    int r = f>>3, c = (f&7)*8;
    *(uint4*)&tile[r][c] = *(const uint4*)(src + (size_t)r*DHH + c);
  }
  __syncthreads();
  unsigned short* dst = vt + ((size_t)bh*DHH + d0)*SS + s0;
  #pragma unroll
  for (int j=0;j<2;j++){
    int f = threadIdx.x + j*256;
    int dr = f>>3, sc = (f&7)*8;
    unsigned short tmp[8];
    #pragma unroll
    for (int i=0;i<8;i++) tmp[i] = tile[sc+i][dr];
    *(uint4*)(dst + (size_t)dr*SS + sc) = *(uint4*)tmp;
  }
}

// ---------------------------------------------------------------------------
// Kernel 4: MFMA attention, split-K, atomic fp32 accumulate.
// 576 blocks = 8 bh (XCD-pinned, bid%8) x 72 (qtile 128 rows, 256-wide chunk).
// 8 waves: wave (wr=wid>>1, wc=wid&1): QK rows 32wr x cols 32wc;
//          PV rows 32wr x d-half 128wc. Q register-resident.
// LDS: K dbuf 2x32KB (row 512B, 16B-chunk XOR row&7), Vt dbuf 2x32KB
//      (row 128B, same XOR), W 16KB (row 128B, same XOR). Total 144KB.
// ---------------------------------------------------------------------------
__global__ __launch_bounds__(512) void k_attn(
    const unsigned short* __restrict__ qb, const unsigned short* __restrict__ kb,
    const unsigned short* __restrict__ vt,
    const float* __restrict__ ab, const float* __restrict__ mb,
    float* __restrict__ acc, float* __restrict__ den)
{
  extern __shared__ char sm[];
  char* smK = sm;                 // 2 x 32768
  char* smV = sm + 65536;         // 2 x 32768
  char* smW = sm + 131072;        // 16384

  const int bid = blockIdx.x;
  const int bh  = bid & 7;
  int u = bid >> 3, qi = 0, ci = 0;
  for (int i = 15; i >= 0; --i) {          // deepest qtiles on lowest bids
    int n = (i + 2) >> 1;
    if (u < n) { qi = i; ci = u; break; }
    u -= n;
  }
  const int s0   = qi * 128;
  const int kbeg = ci * 256;
  const int kend = min(kbeg + 256, (qi + 1) * 128);
  const int nkt  = (kend - kbeg) >> 6;     // 2 or 4

  const int tid  = threadIdx.x;
  const int lane = tid & 63;
  const int wid  = tid >> 6;
  const int wr   = wid >> 1, wc = wid & 1;
  const int l15  = lane & 15, lg = lane >> 4;
  const int bhoff = bh * SS;

  const unsigned short* kbh = kb + (size_t)bh*SS*DHH;
  const unsigned short* vth = vt + (size_t)bh*DHH*SS;

  // ---- prologue: stage tile 0, load Q frags + m values ----
  {
    const char* kg = (const char*)kbh + (size_t)kbeg*512;
    char* kl = smK;
    #pragma unroll
    for (int i=0;i<4;i++) {
      int f = tid + i*512;
      int r = f >> 5, ch = f & 31;
      gload_lds16(kl + (size_t)f*16, kg + (size_t)r*512 + ((ch ^ (r & 7))<<4));
    }
    const char* vg = (const char*)vth + (size_t)kbeg*2;
    char* vl = smV;
    #pragma unroll
    for (int i=0;i<4;i++) {
      int f = tid + i*512;
      int d = f >> 3, ch = f & 7;
      gload_lds16(vl + (size_t)f*16, vg + (size_t)d*4096 + ((ch ^ (d & 7))<<4));
    }
  }

  short8 qf[2][8];
  {
    const unsigned short* qp = qb + ((size_t)bh*SS + s0 + 32*wr)*DHH;
    #pragma unroll
    for (int mt=0; mt<2; ++mt)
      #pragma unroll
      for (int ks=0; ks<8; ++ks)
        qf[mt][ks] = *(const short8*)(qp + (16*mt + l15)*DHH + 32*ks + 8*lg);
  }
  float mrow[2][4];
  #pragma unroll
  for (int mt=0; mt<2; ++mt)
    #pragma unroll
    for (int rr=0; rr<4; ++rr)
      mrow[mt][rr] = mb[bhoff + s0 + 32*wr + 16*mt + 4*lg + rr];

  f32x4 oacc[2][8];
  #pragma unroll
  for (int mt=0; mt<2; ++mt)
    #pragma unroll
    for (int nt=0; nt<8; ++nt)
      oacc[mt][nt] = (f32x4){0.f,0.f,0.f,0.f};
  float denp[2][4] = {{0.f,0.f,0.f,0.f},{0.f,0.f,0.f,0.f}};

  __syncthreads();

  int cur = 0;
  for (int kt = 0; kt < nkt; ++kt) {
    const int t0 = kbeg + kt*64;
    if (kt + 1 < nkt) {        // stage next tile into other buffer
      const int tn = t0 + 64;
      const char* kg = (const char*)kbh + (size_t)tn*512;
      char* kl = smK + (cur^1)*32768;
      #pragma unroll
      for (int i=0;i<4;i++) {
        int f = tid + i*512;
        int r = f >> 5, ch = f & 31;
        gload_lds16(kl + (size_t)f*16, kg + (size_t)r*512 + ((ch ^ (r & 7))<<4));
      }
      const char* vg = (const char*)vth + (size_t)tn*2;
      char* vl = smV + (cur^1)*32768;
      #pragma unroll
      for (int i=0;i<4;i++) {
        int f = tid + i*512;
        int d = f >> 3, ch = f & 7;
        gload_lds16(vl + (size_t)f*16, vg + (size_t)d*4096 + ((ch ^ (d & 7))<<4));
      }
    }
    char* kl = smK + cur*32768;
    char* vl = smV + cur*32768;

    // ---- QK^T (K pre-scaled by 1/16) ----
    f32x4 sacc[2][2];
    #pragma unroll
    for (int mt=0; mt<2; ++mt)
      #pragma unroll
      for (int nt=0; nt<2; ++nt)
        sacc[mt][nt] = (f32x4){0.f,0.f,0.f,0.f};
    #pragma unroll
    for (int ks=0; ks<8; ++ks) {
      #pragma unroll
      for (int nt=0; nt<2; ++nt) {
        const int trel = 32*wc + 16*nt + l15;
        short8 kf = *(const short8*)(kl + (size_t)trel*512 + (((4*ks + lg) ^ (trel & 7))<<4));
        sacc[0][nt] = __builtin_amdgcn_mfma_f32_16x16x32_bf16(qf[0][ks], kf, sacc[0][nt], 0, 0, 0);
        sacc[1][nt] = __builtin_amdgcn_mfma_f32_16x16x32_bf16(qf[1][ks], kf, sacc[1][nt], 0, 0, 0);
      }
    }

    // ---- weights: w = mask * qk * exp(a[t]-m[s]); write W bf16 to LDS ----
    const float a0 = ab[bhoff + t0 + 32*wc + l15];
    const float a1 = ab[bhoff + t0 + 32*wc + 16 + l15];
    #pragma unroll
    for (int mt=0; mt<2; ++mt) {
      #pragma unroll
      for (int nt=0; nt<2; ++nt) {
        const int trel = 32*wc + 16*nt + l15;
        const int tabs = t0 + trel;
        const float av = nt ? a1 : a0;
        #pragma unroll
        for (int rr=0; rr<4; ++rr) {
          const int srel = 32*wr + 16*mt + 4*lg + rr;
          const int sabs = s0 + srel;
          float w = (tabs <= sabs) ? sacc[mt][nt][rr] * __expf(av - mrow[mt][rr]) : 0.f;
          denp[mt][rr] += w;
          *(unsigned short*)(smW + (size_t)srel*128 + (((trel >> 3) ^ (srel & 7))<<4)
                              + ((trel & 7)<<1)) = f2b(w);
        }
      }
    }
    __syncthreads();   // W visible; staged loads drained (compiler vmcnt)

    // ---- PV: oacc += W @ V ----
    #pragma unroll
    for (int kst=0; kst<2; ++kst) {
      const int sr0 = 32*wr + l15;
      const int sr1 = 32*wr + 16 + l15;
      short8 wf0 = *(const short8*)(smW + (size_t)sr0*128 + (((4*kst + lg) ^ (sr0 & 7))<<4));
      short8 wf1 = *(const short8*)(smW + (size_t)sr1*128 + (((4*kst + lg) ^ (sr1 & 7))<<4));
      #pragma unroll
      for (int nt=0; nt<8; ++nt) {
        const int d = 128*wc + 16*nt + l15;
        short8 vf = *(const short8*)(vl + (size_t)d*128 + (((4*kst + lg) ^ (d & 7))<<4));
        oacc[0][nt] = __builtin_amdgcn_mfma_f32_16x16x32_bf16(wf0, vf, oacc[0][nt], 0, 0, 0);
        oacc[1][nt] = __builtin_amdgcn_mfma_f32_16x16x32_bf16(wf1, vf, oacc[1][nt], 0, 0, 0);
      }
    }
    __syncthreads();   // PV done before next iter overwrites W / cur buffer
    cur ^= 1;
  }

  // ---- epilogue: atomic accumulate den and O ----
  #pragma unroll
  for (int mt=0; mt<2; ++mt)
    #pragma unroll
    for (int rr=0; rr<4; ++rr) {
      float v = denp[mt][rr];
      v += __shfl_xor(v, 1); v += __shfl_xor(v, 2);
      v += __shfl_xor(v, 4); v += __shfl_xor(v, 8);
      if (l15 == 0)
        atomicAdd(den + bhoff + s0 + 32*wr + 16*mt + 4*lg + rr, v);
    }
  #pragma unroll
  for (int mt=0; mt<2; ++mt)
    #pragma unroll
    for (int nt=0; nt<8; ++nt)
      #pragma unroll
      for (int rr=0; rr<4; ++rr)
        atomicAdd(acc + ((size_t)(bhoff + s0 + 32*wr + 16*mt + 4*lg + rr))*DHH
                      + 128*wc + 16*nt + l15, oacc[mt][nt][rr]);
}

// ---------------------------------------------------------------------------
// Kernel 5: normalizer + per-head LayerNorm + output write.
// One wave per row; grid (8, 512) x 256 threads.
// ---------------------------------------------------------------------------
__global__ __launch_bounds__(256) void k_fin(
    const float* __restrict__ acc, const float* __restrict__ den,
    const float* __restrict__ flr, const float* __restrict__ ln_w,
    float* __restrict__ out)
{
  const int bh = blockIdx.x, b = bh >> 2, h = bh & 3;
  const int row = blockIdx.y*4 + (threadIdx.x >> 6);
  const int lane = threadIdx.x & 63;

  const float* ap = acc + ((size_t)bh*SS + row)*DHH;
  float4 v = *(const float4*)(ap + lane*4);
  const float d = den[bh*SS + row];
  const float f = flr[bh*SS + row];
  const float inv = 1.f / (fmaxf(fabsf(d), f) + 1e-8f);
  float w0 = v.x*inv, w1 = v.y*inv, w2 = v.z*inv, w3 = v.w*inv;
  float s1 = w0+w1+w2+w3;
  float s2 = w0*w0+w1*w1+w2*w2+w3*w3;
  #pragma unroll
  for (int off=1; off<64; off<<=1) {
    s1 += __shfl_xor(s1, off);
    s2 += __shfl_xor(s2, off);
  }
  const float mean = s1 * (1.f/DHH);
  const float var  = s2 * (1.f/DHH) - mean*mean;
  const float rstd = rsqrtf(var + 1e-5f);
  const float4 g4 = *(const float4*)(ln_w + h*DHH + lane*4);
  float4 o;
  o.x = (w0-mean)*rstd*(1.f+g4.x);
  o.y = (w1-mean)*rstd*(1.f+g4.y);
  o.z = (w2-mean)*rstd*(1.f+g4.z);
  o.w = (w3-mean)*rstd*(1.f+g4.w);
  *(float4*)(out + ((size_t)(b*SS + row))*DD + h*DHH + lane*4) = o;
}

// ---------------------------------------------------------------------------
extern "C" void kernel_launch(void* const* d_in, const int* in_sizes, int n_in,
                              void* d_out, int out_size, void* d_ws, size_t ws_size,
                              hipStream_t stream) {
  (void)in_sizes; (void)n_in; (void)out_size; (void)ws_size;
  const float* x    = (const float*)d_in[0];
  const float* wq   = (const float*)d_in[1];
  const float* wk   = (const float*)d_in[2];
  const float* wv   = (const float*)d_in[3];
  const float* wi   = (const float*)d_in[4];
  const float* bi   = (const float*)d_in[5];
  const float* wf   = (const float*)d_in[6];
  const float* bf   = (const float*)d_in[7];
  const float* ln_w = (const float*)d_in[8];
  float* out = (float*)d_out;
  char* ws = (char*)d_ws;

  unsigned short* QB = (unsigned short*)(ws + QB_OFF);
  unsigned short* KB = (unsigned short*)(ws + KB_OFF);
  unsigned short* VT = (unsigned short*)(ws + VT_OFF);
  unsigned short* VB = (unsigned short*)(ws + VB_OFF);
  float* ACC = (float*)(ws + ACC_OFF);
  float* DEN = (float*)(ws + DEN_OFF);
  float* IG  = (float*)(ws + IG_OFF);
  float* LSF = (float*)(ws + LSF_OFF);
  float* AA  = (float*)(ws + AA_OFF);
  float* MM  = (float*)(ws + MM_OFF);
  float* FLR = (float*)(ws + FLR_OFF);

  k_proj<<<BB*SS, 256, 0, stream>>>(x, wq, wk, wv, wi, bi, wf, bf, QB, KB, VB, IG, LSF);
  k_scan<<<BHH, 256, 0, stream>>>(IG, LSF, AA, MM, FLR);
  k_vt<<<dim3(BHH, SS/64, DHH/64), 256, 0, stream>>>(VB, VT);
  // zero acc + den (16 MB + 64 KB, contiguous); VB is dead now.
  hipMemsetAsync(ws + ACC_OFF, 0, ((size_t)16<<20) + ((size_t)64<<10), stream);
  k_attn<<<576, 512, 147456, stream>>>(QB, KB, VT, AA, MM, ACC, DEN);
  k_fin<<<dim3(BHH, SS/4), 256, 0, stream>>>(ACC, DEN, FLR, ln_w, out);
}

// Round 3
// 106.533 us; speedup vs baseline: 11.1760x; 1.5335x over previous
//
#include <hip/hip_runtime.h>
#include <math.h>

// ---------------------------------------------------------------------------
// mLSTM cell, MFMA bf16, no-atomics version.
// Pipeline: k_gw (gate weight pre-sum) ; k_proj (fp32->bf16 QKV + gate GEMVs)
//           -> k_scan (cumsum/prefix-max) -> k_vt (V transpose)
//           -> k_attn (MFMA, one block per 64-row q-tile, full K sweep,
//                      fused normalizer + headwise LN + output write).
// Identities: a[t]=ig[t]-cs[t], m[s]=prefix-max a, D=exp(a[t]-m[s]),
//   floor[s]=exp(-(cs[s]+m[s])); row work is additive in t.
// ---------------------------------------------------------------------------

#define BB   2
#define SS   2048
#define DD   1024
#define NHH  4
#define DHH  256
#define BHH  (BB*NHH)

// Workspace byte offsets (total ~32.5 MB)
#define QB_OFF   ((size_t)0)
#define KB_OFF   ((size_t)8  << 20)
#define VT_OFF   ((size_t)16 << 20)
#define VB_OFF   ((size_t)24 << 20)
#define IG_OFF   ((size_t)32 << 20)
#define LSF_OFF  (IG_OFF  + ((size_t)64<<10))
#define AA_OFF   (LSF_OFF + ((size_t)64<<10))
#define MM_OFF   (AA_OFF  + ((size_t)64<<10))
#define FLR_OFF  (MM_OFF  + ((size_t)64<<10))
#define WSI_OFF  (FLR_OFF + ((size_t)64<<10))
#define WSF_OFF  (WSI_OFF + ((size_t)32<<10))

typedef __attribute__((ext_vector_type(8))) short short8;   // 8 bf16 (4 VGPR)
typedef __attribute__((ext_vector_type(4))) float f32x4;

typedef const __attribute__((address_space(1))) unsigned int* gas1_u32;
typedef __attribute__((address_space(3))) unsigned int* las3_u32;

__device__ __forceinline__ unsigned short f2b(float f) {
  union { float f; unsigned int u; } v; v.f = f;
  unsigned int r = (v.u + 0x7FFFu + ((v.u >> 16) & 1u)) >> 16;
  return (unsigned short)r;
}

__device__ __forceinline__ void gload_lds16(void* lds, const void* g) {
  __builtin_amdgcn_global_load_lds((gas1_u32)g, (las3_u32)lds, 16, 0, 0);
}

// ---------------------------------------------------------------------------
// Kernel 0: gate weight pre-sum: wsum[n][c] = sum of 3 D-segments.
// ---------------------------------------------------------------------------
__global__ __launch_bounds__(256) void k_gw(
    const float* __restrict__ wi, const float* __restrict__ wf,
    float* __restrict__ wsi, float* __restrict__ wsf)
{
  const int idx = blockIdx.x*256 + threadIdx.x;   // 0..8191
  const int n = idx >> 10, c = idx & 1023;
  wsi[idx] = wi[n*3*DD + c] + wi[n*3*DD + DD + c] + wi[n*3*DD + 2*DD + c];
  wsf[idx] = wf[n*3*DD + c] + wf[n*3*DD + DD + c] + wf[n*3*DD + 2*DD + c];
}

// ---------------------------------------------------------------------------
// Kernel 1: headwise QKV projection (4x4 blocks) + gate GEMVs. bf16 outputs.
// ---------------------------------------------------------------------------
__global__ __launch_bounds__(256) void k_proj(
    const float* __restrict__ x,
    const float* __restrict__ wq, const float* __restrict__ wk, const float* __restrict__ wv,
    const float* __restrict__ wsi, const float* __restrict__ bi,
    const float* __restrict__ wsf, const float* __restrict__ bf,
    unsigned short* __restrict__ qb, unsigned short* __restrict__ kb,
    unsigned short* __restrict__ vb, float* __restrict__ ig, float* __restrict__ lsf)
{
  const int row = blockIdx.x;          // b*SS + s
  const int b   = row >> 11;
  const int s   = row & (SS-1);
  const int g   = threadIdx.x;         // qkv head 0..255

  const float4 xv = *(const float4*)(x + (size_t)row*DD + (g<<2));

  const int h   = g >> 6;
  const int dh0 = (g & 63) << 2;
  const size_t qi = ((size_t)(b*NHH + h)*SS + s)*DHH + dh0;

  {
    const float4 w0 = *(const float4*)(wq + g*16 + 0);
    const float4 w1 = *(const float4*)(wq + g*16 + 4);
    const float4 w2 = *(const float4*)(wq + g*16 + 8);
    const float4 w3 = *(const float4*)(wq + g*16 + 12);
    ushort4 r;
    r.x = f2b(w0.x*xv.x + w0.y*xv.y + w0.z*xv.z + w0.w*xv.w);
    r.y = f2b(w1.x*xv.x + w1.y*xv.y + w1.z*xv.z + w1.w*xv.w);
    r.z = f2b(w2.x*xv.x + w2.y*xv.y + w2.z*xv.z + w2.w*xv.w);
    r.w = f2b(w3.x*xv.x + w3.y*xv.y + w3.z*xv.z + w3.w*xv.w);
    *(ushort4*)(qb + qi) = r;
  }
  {
    const float4 w0 = *(const float4*)(wk + g*16 + 0);
    const float4 w1 = *(const float4*)(wk + g*16 + 4);
    const float4 w2 = *(const float4*)(wk + g*16 + 8);
    const float4 w3 = *(const float4*)(wk + g*16 + 12);
    ushort4 r;
    r.x = f2b(0.0625f*(w0.x*xv.x + w0.y*xv.y + w0.z*xv.z + w0.w*xv.w));
    r.y = f2b(0.0625f*(w1.x*xv.x + w1.y*xv.y + w1.z*xv.z + w1.w*xv.w));
    r.z = f2b(0.0625f*(w2.x*xv.x + w2.y*xv.y + w2.z*xv.z + w2.w*xv.w));
    r.w = f2b(0.0625f*(w3.x*xv.x + w3.y*xv.y + w3.z*xv.z + w3.w*xv.w));
    *(ushort4*)(kb + qi) = r;
  }
  {
    const float4 w0 = *(const float4*)(wv + g*16 + 0);
    const float4 w1 = *(const float4*)(wv + g*16 + 4);
    const float4 w2 = *(const float4*)(wv + g*16 + 8);
    const float4 w3 = *(const float4*)(wv + g*16 + 12);
    ushort4 r;
    r.x = f2b(w0.x*xv.x + w0.y*xv.y + w0.z*xv.z + w0.w*xv.w);
    r.y = f2b(w1.x*xv.x + w1.y*xv.y + w1.z*xv.z + w1.w*xv.w);
    r.z = f2b(w2.x*xv.x + w2.y*xv.y + w2.z*xv.z + w2.w*xv.w);
    r.w = f2b(w3.x*xv.x + w3.y*xv.y + w3.z*xv.z + w3.w*xv.w);
    *(ushort4*)(vb + qi) = r;
  }

  float pi[4], pf[4];
  const int c = g << 2;
  #pragma unroll
  for (int n=0;n<4;n++) {
    const float4 a0 = *(const float4*)(wsi + n*DD + c);
    pi[n] = a0.x*xv.x + a0.y*xv.y + a0.z*xv.z + a0.w*xv.w;
    const float4 b0 = *(const float4*)(wsf + n*DD + c);
    pf[n] = b0.x*xv.x + b0.y*xv.y + b0.z*xv.z + b0.w*xv.w;
  }
  #pragma unroll
  for (int off=32; off>0; off>>=1) {
    #pragma unroll
    for (int n=0;n<4;n++) {
      pi[n] += __shfl_down(pi[n], off);
      pf[n] += __shfl_down(pf[n], off);
    }
  }
  __shared__ float red[4][8];
  const int lane = g & 63, wid = g >> 6;
  if (lane == 0) {
    #pragma unroll
    for (int n=0;n<4;n++) { red[wid][n] = pi[n]; red[wid][4+n] = pf[n]; }
  }
  __syncthreads();
  if (g < 4) {
    const int n = g;
    float ti = red[0][n]+red[1][n]+red[2][n]+red[3][n] + bi[n];
    float tf = red[0][4+n]+red[1][4+n]+red[2][4+n]+red[3][4+n] + bf[n];
    ig[(size_t)(b*NHH+n)*SS + s] = ti;
    float ls = (tf >= 0.f) ? -log1pf(expf(-tf)) : (tf - log1pf(expf(tf)));
    lsf[(size_t)(b*NHH+n)*SS + s] = ls;
  }
}

// ---------------------------------------------------------------------------
// Kernel 2: per-(b,head) scan.
// ---------------------------------------------------------------------------
__global__ __launch_bounds__(256) void k_scan(
    const float* __restrict__ ig, const float* __restrict__ lsf,
    float* __restrict__ aa, float* __restrict__ mm, float* __restrict__ flr)
{
  const int bh = blockIdx.x;
  const int tid = threadIdx.x;
  const float* igp = ig + (size_t)bh*SS;
  const float* lsp = lsf + (size_t)bh*SS;
  float* ap = aa + (size_t)bh*SS;
  float* mp = mm + (size_t)bh*SS;
  float* fp = flr + (size_t)bh*SS;

  __shared__ float sb[256];
  const int base = tid*8;
  float l[8], c[8];
  #pragma unroll
  for (int j=0;j<8;j++) l[j] = lsp[base+j];
  c[0] = l[0];
  #pragma unroll
  for (int j=1;j<8;j++) c[j] = c[j-1] + l[j];

  sb[tid] = c[7];
  __syncthreads();
  for (int off=1; off<256; off<<=1) {
    float v = sb[tid];
    float u = (tid>=off) ? sb[tid-off] : 0.f;
    __syncthreads();
    sb[tid] = v + u;
    __syncthreads();
  }
  const float exs = (tid==0) ? 0.f : sb[tid-1];

  float cs[8], a8[8], mx[8];
  #pragma unroll
  for (int j=0;j<8;j++) { cs[j] = exs + c[j]; a8[j] = igp[base+j] - cs[j]; }
  mx[0] = a8[0];
  #pragma unroll
  for (int j=1;j<8;j++) mx[j] = fmaxf(mx[j-1], a8[j]);

  __syncthreads();
  sb[tid] = mx[7];
  __syncthreads();
  for (int off=1; off<256; off<<=1) {
    float v = sb[tid];
    float u = (tid>=off) ? sb[tid-off] : -INFINITY;
    __syncthreads();
    sb[tid] = fmaxf(v, u);
    __syncthreads();
  }
  const float exm = (tid==0) ? -INFINITY : sb[tid-1];

  #pragma unroll
  for (int j=0;j<8;j++) {
    float mmx = fmaxf(exm, mx[j]);
    ap[base+j] = a8[j];
    mp[base+j] = mmx;
    fp[base+j] = expf(-(cs[j] + mmx));
  }
}

// ---------------------------------------------------------------------------
// Kernel 3: transpose V bf16 [bh][s][d] -> Vt [bh][d][s].
// ---------------------------------------------------------------------------
__global__ __launch_bounds__(256) void k_vt(
    const unsigned short* __restrict__ vb, unsigned short* __restrict__ vt)
{
  __shared__ unsigned short tile[64][72];
  const int bh = blockIdx.x, st = blockIdx.y, dt = blockIdx.z;
  const int s0 = st*64, d0 = dt*64;
  const unsigned short* src = vb + ((size_t)bh*SS + s0)*DHH + d0;
  #pragma unroll
  for (int j=0;j<2;j++){
    int f = threadIdx.x + j*256;           // 0..511
    int r = f>>3, c = (f&7)*8;
    *(uint4*)&tile[r][c] = *(const uint4*)(src + (size_t)r*DHH + c);
  }
  __syncthreads();
  unsigned short* dst = vt + ((size_t)bh*DHH + d0)*SS + s0;
  #pragma unroll
  for (int j=0;j<2;j++){
    int f = threadIdx.x + j*256;
    int dr = f>>3, sc = (f&7)*8;
    unsigned short tmp[8];
    #pragma unroll
    for (int i=0;i<8;i++) tmp[i] = tile[sc+i][dr];
    *(uint4*)(dst + (size_t)dr*SS + sc) = *(uint4*)tmp;
  }
}

// ---------------------------------------------------------------------------
// Kernel 4: MFMA attention. 256 blocks = 8 bh (XCD-pinned) x 32 row-tiles of
// 64 q-rows. Each block sweeps K-range [0, s0+64) with K/Vt double-buffered
// in LDS (global_load_lds w16, 16B-chunk XOR swizzle); fused normalizer +
// per-head LayerNorm + output write. No atomics, no extra passes.
// 8 waves: wr=wid>>2 (32-row band), wc=wid&3 (16-col QKT strip / 64-d slice).
// LDS: K 2x32KB, Vt 2x32KB, W 8KB, red 3KB = 142336 B (1 block/CU).
// ---------------------------------------------------------------------------
__global__ __launch_bounds__(512) void k_attn(
    const unsigned short* __restrict__ qb, const unsigned short* __restrict__ kb,
    const unsigned short* __restrict__ vt,
    const float* __restrict__ ab, const float* __restrict__ mb,
    const float* __restrict__ flr, const float* __restrict__ ln_w,
    float* __restrict__ out)
{
  extern __shared__ char sm[];
  char* smK = sm;                          // 2 x 32768
  char* smV = sm + 65536;                  // 2 x 32768
  char* smW = sm + 131072;                 // 8192 (64 rows x 128B, swizzled)
  float* smRed = (float*)(sm + 139264);    // 64 x 4
  float* smS1  = smRed + 256;              // 64 x 4
  float* smS2  = smS1 + 256;               // 64 x 4

  const int bid = blockIdx.x;
  const int bh  = bid & 7;                 // XCD pin
  const int rt  = bid >> 3;                // 0..31
  const int s0  = rt * 64;
  const int nkt = rt + 1;

  const int tid  = threadIdx.x;
  const int lane = tid & 63;
  const int wid  = tid >> 6;
  const int wr   = wid >> 2;               // 0..1
  const int wc   = wid & 3;                // 0..3
  const int l15  = lane & 15, lg = lane >> 4;
  const int bhoff = bh * SS;
  const int b = bh >> 2, h = bh & 3;

  const unsigned short* kbh = kb + (size_t)bh*SS*DHH;
  const unsigned short* vth = vt + (size_t)bh*DHH*SS;

  // ---- prologue: stage tile 0 ----
  {
    const char* kg = (const char*)kbh;     // t0 = 0
    #pragma unroll
    for (int i=0;i<4;i++) {
      int f = tid + i*512;
      int r = f >> 5, ch = f & 31;
      gload_lds16(smK + (size_t)f*16, kg + (size_t)r*512 + ((ch ^ (r & 7))<<4));
    }
    const char* vg = (const char*)vth;
    #pragma unroll
    for (int i=0;i<4;i++) {
      int f = tid + i*512;
      int d = f >> 3, ch = f & 7;
      gload_lds16(smV + (size_t)f*16, vg + (size_t)d*4096 + ((ch ^ (d & 7))<<4));
    }
  }

  // Q register-resident: rows 32*wr band
  short8 qf[2][8];
  {
    const unsigned short* qp = qb + ((size_t)bh*SS + s0 + 32*wr)*DHH;
    #pragma unroll
    for (int mt=0; mt<2; ++mt)
      #pragma unroll
      for (int ks=0; ks<8; ++ks)
        qf[mt][ks] = *(const short8*)(qp + (16*mt + l15)*DHH + 32*ks + 8*lg);
  }
  float mrow[2][4];
  #pragma unroll
  for (int mt=0; mt<2; ++mt)
    #pragma unroll
    for (int rr=0; rr<4; ++rr)
      mrow[mt][rr] = mb[bhoff + s0 + 32*wr + 16*mt + 4*lg + rr];

  f32x4 oacc[2][4];
  #pragma unroll
  for (int mt=0; mt<2; ++mt)
    #pragma unroll
    for (int nt=0; nt<4; ++nt)
      oacc[mt][nt] = (f32x4){0.f,0.f,0.f,0.f};
  float denp[2][4] = {{0.f,0.f,0.f,0.f},{0.f,0.f,0.f,0.f}};

  const int trel = 16*wc + l15;            // QKT col within tile, 0..63

  __syncthreads();

  int cur = 0;
  for (int kt = 0; kt < nkt; ++kt) {
    const int t0 = kt*64;
    if (kt + 1 < nkt) {                    // stage next tile into other buffer
      const int tn = t0 + 64;
      const char* kg = (const char*)kbh + (size_t)tn*512;
      char* kl = smK + (cur^1)*32768;
      #pragma unroll
      for (int i=0;i<4;i++) {
        int f = tid + i*512;
        int r = f >> 5, ch = f & 31;
        gload_lds16(kl + (size_t)f*16, kg + (size_t)r*512 + ((ch ^ (r & 7))<<4));
      }
      const char* vg = (const char*)vth + (size_t)tn*2;
      char* vl = smV + (cur^1)*32768;
      #pragma unroll
      for (int i=0;i<4;i++) {
        int f = tid + i*512;
        int d = f >> 3, ch = f & 7;
        gload_lds16(vl + (size_t)f*16, vg + (size_t)d*4096 + ((ch ^ (d & 7))<<4));
      }
    }
    char* kl = smK + cur*32768;
    char* vl = smV + cur*32768;

    // ---- QK^T (K pre-scaled by 1/16): wave computes 32 rows x 16 cols ----
    f32x4 sacc[2];
    sacc[0] = (f32x4){0.f,0.f,0.f,0.f};
    sacc[1] = (f32x4){0.f,0.f,0.f,0.f};
    #pragma unroll
    for (int ks=0; ks<8; ++ks) {
      short8 kf = *(const short8*)(kl + (size_t)trel*512 + (((4*ks + lg) ^ (trel & 7))<<4));
      sacc[0] = __builtin_amdgcn_mfma_f32_16x16x32_bf16(qf[0][ks], kf, sacc[0], 0, 0, 0);
      sacc[1] = __builtin_amdgcn_mfma_f32_16x16x32_bf16(qf[1][ks], kf, sacc[1], 0, 0, 0);
    }

    // ---- weights: w = mask * qk * exp(a[t]-m[s]); bf16 into swizzled LDS ----
    const float av = ab[bhoff + t0 + trel];
    const int tabs = t0 + trel;
    const bool diag = (kt == nkt-1);
    #pragma unroll
    for (int mt=0; mt<2; ++mt) {
      #pragma unroll
      for (int rr=0; rr<4; ++rr) {
        const int srel = 32*wr + 16*mt + 4*lg + rr;
        float w = sacc[mt][rr] * __expf(av - mrow[mt][rr]);
        if (diag && (tabs > s0 + srel)) w = 0.f;
        denp[mt][rr] += w;
        *(unsigned short*)(smW + (size_t)srel*128 + (((trel >> 3) ^ (srel & 7))<<4)
                            + ((trel & 7)<<1)) = f2b(w);
      }
    }
    __syncthreads();   // W visible; staged loads drained

    // ---- PV: oacc += W @ V ; wave: 32 rows x 64-d slice ----
    #pragma unroll
    for (int kst=0; kst<2; ++kst) {
      const int sr0 = 32*wr + l15;
      const int sr1 = 32*wr + 16 + l15;
      short8 wf0 = *(const short8*)(smW + (size_t)sr0*128 + (((4*kst + lg) ^ (sr0 & 7))<<4));
      short8 wf1 = *(const short8*)(smW + (size_t)sr1*128 + (((4*kst + lg) ^ (sr1 & 7))<<4));
      #pragma unroll
      for (int nt=0; nt<4; ++nt) {
        const int d = 64*wc + 16*nt + l15;
        short8 vf = *(const short8*)(vl + (size_t)d*128 + (((4*kst + lg) ^ (d & 7))<<4));
        oacc[0][nt] = __builtin_amdgcn_mfma_f32_16x16x32_bf16(wf0, vf, oacc[0][nt], 0, 0, 0);
        oacc[1][nt] = __builtin_amdgcn_mfma_f32_16x16x32_bf16(wf1, vf, oacc[1][nt], 0, 0, 0);
      }
    }
    __syncthreads();   // PV done before next iter overwrites W / cur buffer
    cur ^= 1;
  }

  // ---- epilogue: den reduce (lanes then wc-waves), normalizer, LN, write ----
  #pragma unroll
  for (int mt=0; mt<2; ++mt)
    #pragma unroll
    for (int rr=0; rr<4; ++rr) {
      float v = denp[mt][rr];
      v += __shfl_xor(v, 1); v += __shfl_xor(v, 2);
      v += __shfl_xor(v, 4); v += __shfl_xor(v, 8);
      if (l15 == 0) smRed[(32*wr + 16*mt + 4*lg + rr)*4 + wc] = v;
    }
  __syncthreads();

  float inv[2][4];
  #pragma unroll
  for (int mt=0; mt<2; ++mt)
    #pragma unroll
    for (int rr=0; rr<4; ++rr) {
      const int srel = 32*wr + 16*mt + 4*lg + rr;
      float dsum = smRed[srel*4+0] + smRed[srel*4+1] + smRed[srel*4+2] + smRed[srel*4+3];
      float f = flr[bhoff + s0 + srel];
      inv[mt][rr] = 1.f / (fmaxf(fabsf(dsum), f) + 1e-8f);
    }

  float s1p[2][4] = {{0,0,0,0},{0,0,0,0}}, s2p[2][4] = {{0,0,0,0},{0,0,0,0}};
  #pragma unroll
  for (int mt=0; mt<2; ++mt)
    #pragma unroll
    for (int nt=0; nt<4; ++nt)
      #pragma unroll
      for (int rr=0; rr<4; ++rr) {
        float v = oacc[mt][nt][rr] * inv[mt][rr];
        oacc[mt][nt][rr] = v;
        s1p[mt][rr] += v;
        s2p[mt][rr] += v*v;
      }
  #pragma unroll
  for (int mt=0; mt<2; ++mt)
    #pragma unroll
    for (int rr=0; rr<4; ++rr) {
      float a = s1p[mt][rr], q = s2p[mt][rr];
      a += __shfl_xor(a, 1); a += __shfl_xor(a, 2);
      a += __shfl_xor(a, 4); a += __shfl_xor(a, 8);
      q += __shfl_xor(q, 1); q += __shfl_xor(q, 2);
      q += __shfl_xor(q, 4); q += __shfl_xor(q, 8);
      if (l15 == 0) {
        const int srel = 32*wr + 16*mt + 4*lg + rr;
        smS1[srel*4 + wc] = a;
        smS2[srel*4 + wc] = q;
      }
    }
  __syncthreads();

  float g4[4];
  #pragma unroll
  for (int nt=0; nt<4; ++nt) g4[nt] = 1.f + ln_w[h*DHH + 64*wc + 16*nt + l15];

  #pragma unroll
  for (int mt=0; mt<2; ++mt)
    #pragma unroll
    for (int rr=0; rr<4; ++rr) {
      const int srel = 32*wr + 16*mt + 4*lg + rr;
      const float ms = smS1[srel*4+0] + smS1[srel*4+1] + smS1[srel*4+2] + smS1[srel*4+3];
      const float sq = smS2[srel*4+0] + smS2[srel*4+1] + smS2[srel*4+2] + smS2[srel*4+3];
      const float mean = ms * (1.f/DHH);
      const float var  = sq * (1.f/DHH) - mean*mean;
      const float rstd = rsqrtf(var + 1e-5f);
      float* op = out + ((size_t)(b*SS + s0 + srel))*DD + h*DHH;
      #pragma unroll
      for (int nt=0; nt<4; ++nt)
        op[64*wc + 16*nt + l15] = (oacc[mt][nt][rr] - mean)*rstd*g4[nt];
    }
}

// ---------------------------------------------------------------------------
extern "C" void kernel_launch(void* const* d_in, const int* in_sizes, int n_in,
                              void* d_out, int out_size, void* d_ws, size_t ws_size,
                              hipStream_t stream) {
  (void)in_sizes; (void)n_in; (void)out_size; (void)ws_size;
  const float* x    = (const float*)d_in[0];
  const float* wq   = (const float*)d_in[1];
  const float* wk   = (const float*)d_in[2];
  const float* wv   = (const float*)d_in[3];
  const float* wi   = (const float*)d_in[4];
  const float* bi   = (const float*)d_in[5];
  const float* wf   = (const float*)d_in[6];
  const float* bf   = (const float*)d_in[7];
  const float* ln_w = (const float*)d_in[8];
  float* out = (float*)d_out;
  char* ws = (char*)d_ws;

  unsigned short* QB = (unsigned short*)(ws + QB_OFF);
  unsigned short* KB = (unsigned short*)(ws + KB_OFF);
  unsigned short* VT = (unsigned short*)(ws + VT_OFF);
  unsigned short* VB = (unsigned short*)(ws + VB_OFF);
  float* IG  = (float*)(ws + IG_OFF);
  float* LSF = (float*)(ws + LSF_OFF);
  float* AA  = (float*)(ws + AA_OFF);
  float* MM  = (float*)(ws + MM_OFF);
  float* FLR = (float*)(ws + FLR_OFF);
  float* WSI = (float*)(ws + WSI_OFF);
  float* WSF = (float*)(ws + WSF_OFF);

  k_gw<<<32, 256, 0, stream>>>(wi, wf, WSI, WSF);
  k_proj<<<BB*SS, 256, 0, stream>>>(x, wq, wk, wv, WSI, bi, WSF, bf, QB, KB, VB, IG, LSF);
  k_scan<<<BHH, 256, 0, stream>>>(IG, LSF, AA, MM, FLR);
  k_vt<<<dim3(BHH, SS/64, DHH/64), 256, 0, stream>>>(VB, VT);
  k_attn<<<256, 512, 142336, stream>>>(QB, KB, VT, AA, MM, FLR, ln_w, out);
}